// Round 6
// baseline (189.146 us; speedup 1.0000x reference)
//
#include <hip/hip_runtime.h>

// out = irfft2( rfft2(x_grid) * W ), ortho, grid 16x16, C=768, B=256.
// Per block (b, 32 channels), 256 threads, 3 stages through one 16.5KB LDS
// buffer holding inter-stage spectra as packed f16 pairs (fp32 compute).
// Occupancy notes (R4/R5 post-mortem):
//  - launch_bounds 2nd arg sets the UNIFIED VGPR+AGPR budget = 512/waves.
//    (256,4) -> 128 regs -> 16 waves/CU (occ 39%); (256,8) -> 64 regs ->
//    scratch spill (R4, 1.15GB HBM). (256,6) -> ~80 regs -> 24 waves/CU.
//  - S2 weight loads happen AFTER the forward FFT so peak live regs stay
//    under the 80 budget (32 FFT state + weight window + addrs).

#define DIM 768
#define CT 32
#define NCT (DIM / CT)   // 24
#define IP 258           // half2-entry pitch per i-row: 8 slots * 32 ch + 2 pad

#define R2c  0.70710678118654752f
#define C1c  0.92387953251128674f
#define S1cc 0.38268343236508978f
#define INV512  (1.f / 512.f)
#define INV256  (1.f / 256.f)
#define INV1024 (1.f / 1024.f)

typedef __fp16 h2v __attribute__((ext_vector_type(2)));
union H2U { h2v h; uint32_t u; };

__device__ __forceinline__ uint32_t packh2(float a, float b) {
  H2U t; t.h = __builtin_amdgcn_cvt_pkrtz(a, b); return t.u;
}
__device__ __forceinline__ float2 unpackh2(uint32_t v) {
  H2U t; t.u = v; return make_float2((float)t.h.x, (float)t.h.y);
}

template <int SGN>   // SGN = -1 forward, +1 inverse (unnormalized)
__device__ __forceinline__ void fft16(float* xr, float* xi) {
#define SWP(a, b) { float t_ = xr[a]; xr[a] = xr[b]; xr[b] = t_; t_ = xi[a]; xi[a] = xi[b]; xi[b] = t_; }
  SWP(1, 8) SWP(2, 4) SWP(3, 12) SWP(5, 10) SWP(7, 14) SWP(11, 13)
#undef SWP
#define BF1(a, b) { float tr = xr[b], ti = xi[b]; xr[b] = xr[a] - tr; xi[b] = xi[a] - ti; xr[a] += tr; xi[a] += ti; }
#define BFI(a, b) { float tr, ti; if (SGN < 0) { tr = xi[b]; ti = -xr[b]; } else { tr = -xi[b]; ti = xr[b]; } \
                    xr[b] = xr[a] - tr; xi[b] = xi[a] - ti; xr[a] += tr; xi[a] += ti; }
#define BFW(a, b, Wr, Wi) { float tr = (Wr) * xr[b] - (Wi) * xi[b], ti = (Wr) * xi[b] + (Wi) * xr[b]; \
                            xr[b] = xr[a] - tr; xi[b] = xi[a] - ti; xr[a] += tr; xi[a] += ti; }
  BF1(0, 1) BF1(2, 3) BF1(4, 5) BF1(6, 7) BF1(8, 9) BF1(10, 11) BF1(12, 13) BF1(14, 15)
  BF1(0, 2) BF1(4, 6) BF1(8, 10) BF1(12, 14)
  BFI(1, 3) BFI(5, 7) BFI(9, 11) BFI(13, 15)
  BF1(0, 4) BF1(8, 12)
  BFW(1, 5, R2c, SGN * R2c) BFW(9, 13, R2c, SGN * R2c)
  BFI(2, 6) BFI(10, 14)
  BFW(3, 7, -R2c, SGN * R2c) BFW(11, 15, -R2c, SGN * R2c)
  BF1(0, 8)
  BFW(1, 9, C1c, SGN * S1cc)
  BFW(2, 10, R2c, SGN * R2c)
  BFW(3, 11, S1cc, SGN * C1c)
  BFI(4, 12)
  BFW(5, 13, -S1cc, SGN * C1c)
  BFW(6, 14, -R2c, SGN * R2c)
  BFW(7, 15, -C1c, SGN * S1cc)
#undef BF1
#undef BFI
#undef BFW
}

__global__ __launch_bounds__(256, 6) void gf6_kernel(const float* __restrict__ x,
                                                     const float* __restrict__ w,
                                                     float* __restrict__ out) {
  __shared__ __align__(8) uint32_t E[16 * IP];   // 16.5 KB, U then aliased as Q

  const int blk = blockIdx.x;
  const int ct = blk >> 8;        // 0..23  (ct-outer: W slice L2-hot)
  const int b  = blk & 255;
  const int c0 = ct * CT;
  const int t  = threadIdx.x;
  const int r  = t >> 4;          // i (S1) / n1 (S3)
  const int p  = t & 15;          // channel-pair index

  // ---------------- S1: rfft over j, 2 channels packed ----------------
  {
    const float2* xp = (const float2*)(x + (size_t)b * 196608 + (size_t)r * 12288 + c0) + p;
    float zr[16], zi[16];
#pragma unroll
    for (int j = 0; j < 16; j++) { float2 v = xp[j * 384]; zr[j] = v.x; zi[j] = v.y; }
    fft16<-1>(zr, zi);
    // slot 0: (F_a[0], F_a[8]) , (F_b[0], F_b[8])  (1x scale)
    {
      uint2 v; v.x = packh2(zr[0], zr[8]); v.y = packh2(zi[0], zi[8]);
      *(uint2*)&E[2 * (r * 129 + p)] = v;
    }
    // slots k=1..7: doubled half-spectra A'=2*F_a, B'=2*F_b
#pragma unroll
    for (int k = 1; k <= 7; k++) {
      const int m = 16 - k;
      float Ar = zr[k] + zr[m], Ai = zi[k] - zi[m];
      float Br = zi[k] + zi[m], Bi = zr[m] - zr[k];
      uint2 v; v.x = packh2(Ar, Ai); v.y = packh2(Br, Bi);
      *(uint2*)&E[2 * (r * 129 + k * 16 + p)] = v;
    }
  }
  __syncthreads();

  // ---------------- S2: fft over i, weight, ifft over k1 ----------------
  {
    const int s = t >> 5;         // slot 0..7
    const int c = t & 31;         // channel within tile
    float gr[16], gi[16];
    const uint32_t* col = E + s * 32 + c;
#pragma unroll
    for (int i = 0; i < 16; i++) { float2 v = unpackh2(col[i * IP]); gr[i] = v.x; gi[i] = v.y; }
    __syncthreads();              // all reads of U done before Q overwrites

    if (s == 0) {
      // packed: columns k2=0 and k2=8 (real), folded weights
      fft16<-1>(gr, gi);
      const float* wc = w + (size_t)(c0 + c) * 2;   // per-k1 stride 13824 floats; +12288 for k2=8
      {
        float2 a0 = *(const float2*)(wc);
        float2 a8 = *(const float2*)(wc + 12288);
        float2 b0 = *(const float2*)(wc + 8 * 13824);
        float2 b8 = *(const float2*)(wc + 8 * 13824 + 12288);
        gr[0] = gr[0] * (a0.x * INV256);
        gi[0] = gi[0] * (a8.x * INV256);
        gr[8] = gr[8] * (b0.x * INV256);
        gi[8] = gi[8] * (b8.x * INV256);
      }
#pragma unroll
      for (int k = 1; k <= 7; k++) {
        const int m = 16 - k;
        float2 a0 = *(const float2*)(wc + (size_t)k * 13824);
        float2 m0 = *(const float2*)(wc + (size_t)m * 13824);
        float2 a8 = *(const float2*)(wc + (size_t)k * 13824 + 12288);
        float2 m8 = *(const float2*)(wc + (size_t)m * 13824 + 12288);
        float Vpr = (a0.x + m0.x + a8.x + m8.x) * INV1024;
        float Vpi = (a0.y - m0.y + a8.y - m8.y) * INV1024;
        float Vmr = (a0.x + m0.x - a8.x - m8.x) * INV1024;
        float Vmi = (a0.y - m0.y - a8.y + m8.y) * INV1024;
        float ur = gr[k], ui = gi[k], vr = gr[m], vi = gi[m];
        float nkr = ur * Vpr - ui * Vpi + vr * Vmr + vi * Vmi;
        float nki = ur * Vpi + ui * Vpr + vr * Vmi - vi * Vmr;
        float nmr = vr * Vpr + vi * Vpi + ur * Vmr - ui * Vmi;
        float nmi = vi * Vpr - vr * Vpi - ur * Vmi - ui * Vmr;
        gr[k] = nkr; gi[k] = nki; gr[m] = nmr; gi[m] = nmi;
      }
      fft16<1>(gr, gi);           // (re, im) = (Re Q[.][0], Re Q[.][8])
    } else {
      // regular: column k2 = s (stored doubled -> weight * 1/512).
      // Weights loaded AFTER the forward FFT (L2-hot), consumed in-loop, to
      // keep peak register pressure under the 80-reg budget.
      fft16<-1>(gr, gi);
      const float* wp = w + (size_t)(s * 768 + c0 + c) * 2;
#pragma unroll
      for (int k1 = 0; k1 < 16; k1++) {
        float2 wv = *(const float2*)(wp + (size_t)k1 * 13824);
        const float wr_ = wv.x * INV512, wi_ = wv.y * INV512;
        float yr = gr[k1] * wr_ - gi[k1] * wi_;
        float yi = gr[k1] * wi_ + gi[k1] * wr_;
        gr[k1] = yr; gi[k1] = yi;
      }
      fft16<1>(gr, gi);
    }

    uint32_t* colo = E + s * 32 + c;
#pragma unroll
    for (int n1 = 0; n1 < 16; n1++) { colo[n1 * IP] = packh2(gr[n1], gi[n1]); }
  }
  __syncthreads();

  // ---------------- S3: irfft over k2, 2 channels packed, store ----------------
  {
    float hr[16], hq[16];
#pragma unroll
    for (int k = 0; k <= 7; k++) {
      uint2 v = *(const uint2*)&E[2 * (r * 129 + k * 16 + p)];
      float2 lo = unpackh2(v.x);   // (a.re, a.im)  /  k=0: (Q0_a, Q8_a)
      float2 hi = unpackh2(v.y);   // (b.re, b.im)  /  k=0: (Q0_b, Q8_b)
      if (k == 0) {
        hr[0] = lo.x; hq[0] = hi.x;
        hr[8] = lo.y; hq[8] = hi.y;
      } else {
        hr[k] = lo.x - hi.y;      hq[k] = lo.y + hi.x;
        hr[16 - k] = lo.x + hi.y; hq[16 - k] = hi.x - lo.y;
      }
    }
    fft16<1>(hr, hq);   // (re, im) = (out_a[n2], out_b[n2])
    float2* op = (float2*)(out + (size_t)b * 196608 + (size_t)r * 12288 + c0) + p;
#pragma unroll
    for (int n2 = 0; n2 < 16; n2++) { op[n2 * 384] = make_float2(hr[n2], hq[n2]); }
  }
}

extern "C" void kernel_launch(void* const* d_in, const int* in_sizes, int n_in,
                              void* d_out, int out_size, void* d_ws, size_t ws_size,
                              hipStream_t stream) {
  const float* x = (const float*)d_in[0];
  const float* w = (const float*)d_in[1];
  float* out = (float*)d_out;
  dim3 grid(NCT * 256);   // 24 * 256 = 6144
  dim3 block(256);
  hipLaunchKernelGGL(gf6_kernel, grid, block, 0, stream, x, w, out);
}

// Round 7
// 123.353 us; speedup vs baseline: 1.5334x; 1.5334x over previous
//
#include <hip/hip_runtime.h>

// out = irfft2( rfft2(x_grid) * W ), ortho, grid 16x16, C=768, B=256.
// BARRIER-FREE: each wave owns 8 channels end-to-end through a private
// 4.2KB LDS slice (f16-packed spectra, fp32 compute). Wave-internal DS
// ordering: DS pipe is in-order per wave; every LDS write's data depends on
// all prior LDS reads (FFT mixes all 16), so dataflow forbids reordering;
// asm memory fences at stage boundaries stop compiler hoisting.
// Occupancy (R4-R6 post-mortem): hipcc VGPR cap = 256/launch_bounds_waves;
// FFT state needs ~60 regs -> only (256,4)=64-cap avoids spill -> 16 waves/CU
// is the feasible point; this round removes barrier convoys instead.

#define DIM 768
#define CT 32
#define NCT (DIM / CT)   // 24
#define WCH 8            // channels per wave
#define WPITCH 1056      // per-wave LDS region in u32 (pitch 66 per i-row)

#define R2c  0.70710678118654752f
#define C1c  0.92387953251128674f
#define S1cc 0.38268343236508978f
#define INV512  (1.f / 512.f)
#define INV256  (1.f / 256.f)
#define INV1024 (1.f / 1024.f)

typedef __fp16 h2v __attribute__((ext_vector_type(2)));
union H2U { h2v h; uint32_t u; };

__device__ __forceinline__ uint32_t packh2(float a, float b) {
  H2U t; t.h = __builtin_amdgcn_cvt_pkrtz(a, b); return t.u;
}
__device__ __forceinline__ float2 unpackh2(uint32_t v) {
  H2U t; t.u = v; return make_float2((float)t.h.x, (float)t.h.y);
}

template <int SGN>   // SGN = -1 forward, +1 inverse (unnormalized)
__device__ __forceinline__ void fft16(float* xr, float* xi) {
#define SWP(a, b) { float t_ = xr[a]; xr[a] = xr[b]; xr[b] = t_; t_ = xi[a]; xi[a] = xi[b]; xi[b] = t_; }
  SWP(1, 8) SWP(2, 4) SWP(3, 12) SWP(5, 10) SWP(7, 14) SWP(11, 13)
#undef SWP
#define BF1(a, b) { float tr = xr[b], ti = xi[b]; xr[b] = xr[a] - tr; xi[b] = xi[a] - ti; xr[a] += tr; xi[a] += ti; }
#define BFI(a, b) { float tr, ti; if (SGN < 0) { tr = xi[b]; ti = -xr[b]; } else { tr = -xi[b]; ti = xr[b]; } \
                    xr[b] = xr[a] - tr; xi[b] = xi[a] - ti; xr[a] += tr; xi[a] += ti; }
#define BFW(a, b, Wr, Wi) { float tr = (Wr) * xr[b] - (Wi) * xi[b], ti = (Wr) * xi[b] + (Wi) * xr[b]; \
                            xr[b] = xr[a] - tr; xi[b] = xi[a] - ti; xr[a] += tr; xi[a] += ti; }
  BF1(0, 1) BF1(2, 3) BF1(4, 5) BF1(6, 7) BF1(8, 9) BF1(10, 11) BF1(12, 13) BF1(14, 15)
  BF1(0, 2) BF1(4, 6) BF1(8, 10) BF1(12, 14)
  BFI(1, 3) BFI(5, 7) BFI(9, 11) BFI(13, 15)
  BF1(0, 4) BF1(8, 12)
  BFW(1, 5, R2c, SGN * R2c) BFW(9, 13, R2c, SGN * R2c)
  BFI(2, 6) BFI(10, 14)
  BFW(3, 7, -R2c, SGN * R2c) BFW(11, 15, -R2c, SGN * R2c)
  BF1(0, 8)
  BFW(1, 9, C1c, SGN * S1cc)
  BFW(2, 10, R2c, SGN * R2c)
  BFW(3, 11, S1cc, SGN * C1c)
  BFI(4, 12)
  BFW(5, 13, -S1cc, SGN * C1c)
  BFW(6, 14, -R2c, SGN * R2c)
  BFW(7, 15, -C1c, SGN * S1cc)
#undef BF1
#undef BFI
#undef BFW
}

__global__ __launch_bounds__(256, 4) void gf7_kernel(const float* __restrict__ x,
                                                     const float* __restrict__ w,
                                                     float* __restrict__ out) {
  __shared__ __align__(16) uint32_t E[4 * WPITCH];   // 16.9 KB, 4.2KB per wave

  const int blk = blockIdx.x;
  const int ct = blk >> 8;        // 0..23  (ct-outer: W slice L2-hot)
  const int b  = blk & 255;
  const int t  = threadIdx.x;
  const int wv = t >> 6;          // wave 0..3
  const int l  = t & 63;          // lane
  uint32_t* Ew = E + wv * WPITCH;
  const int cb = ct * CT + wv * WCH;   // wave's first channel

  // ---------------- S1: rfft over j, 2 channels packed, lane=(i,pp) --------
  {
    const int i = l >> 2, pp = l & 3;
    const float2* xp = (const float2*)(x + (size_t)b * 196608 + (size_t)i * 12288 + cb) + pp;
    float zr[16], zi[16];
#pragma unroll
    for (int j = 0; j < 16; j++) { float2 v = xp[j * 384]; zr[j] = v.x; zi[j] = v.y; }
    fft16<-1>(zr, zi);
    // slot 0: per channel packed (F[0], F[8]) (both real, 1x scale)
    {
      uint2 v; v.x = packh2(zr[0], zr[8]); v.y = packh2(zi[0], zi[8]);
      *(uint2*)&Ew[66 * i + 2 * pp] = v;
    }
    // slots k=1..7: doubled half-spectra A'=2*F_a, B'=2*F_b
#pragma unroll
    for (int k = 1; k <= 7; k++) {
      const int m = 16 - k;
      float Ar = zr[k] + zr[m], Ai = zi[k] - zi[m];
      float Br = zi[k] + zi[m], Bi = zr[m] - zr[k];
      uint2 v; v.x = packh2(Ar, Ai); v.y = packh2(Br, Bi);
      *(uint2*)&Ew[66 * i + 8 * k + 2 * pp] = v;
    }
  }
  asm volatile("" ::: "memory");   // order S1 LDS writes before S2 LDS reads

  // ---------------- S2: fft over i, weight, ifft over k1; lane=(s,ch) ------
  {
    const int s = l >> 3, ch = l & 7;
    float gr[16], gi[16];
#pragma unroll
    for (int i = 0; i < 16; i++) { float2 v = unpackh2(Ew[66 * i + l]); gr[i] = v.x; gi[i] = v.y; }
    fft16<-1>(gr, gi);

    const int c = cb + ch;
    if (s == 0) {
      // packed: columns k2=0 and k2=8 (real), folded weights
      const float* wc = w + (size_t)c * 2;   // per-k1 stride 13824 floats; +12288 for k2=8
      {
        float2 a0 = *(const float2*)(wc);
        float2 a8 = *(const float2*)(wc + 12288);
        float2 b0 = *(const float2*)(wc + 8 * 13824);
        float2 b8 = *(const float2*)(wc + 8 * 13824 + 12288);
        gr[0] = gr[0] * (a0.x * INV256);
        gi[0] = gi[0] * (a8.x * INV256);
        gr[8] = gr[8] * (b0.x * INV256);
        gi[8] = gi[8] * (b8.x * INV256);
      }
#pragma unroll
      for (int k = 1; k <= 7; k++) {
        const int m = 16 - k;
        float2 a0 = *(const float2*)(wc + (size_t)k * 13824);
        float2 m0 = *(const float2*)(wc + (size_t)m * 13824);
        float2 a8 = *(const float2*)(wc + (size_t)k * 13824 + 12288);
        float2 m8 = *(const float2*)(wc + (size_t)m * 13824 + 12288);
        float Vpr = (a0.x + m0.x + a8.x + m8.x) * INV1024;
        float Vpi = (a0.y - m0.y + a8.y - m8.y) * INV1024;
        float Vmr = (a0.x + m0.x - a8.x - m8.x) * INV1024;
        float Vmi = (a0.y - m0.y - a8.y + m8.y) * INV1024;
        float ur = gr[k], ui = gi[k], vr = gr[m], vi = gi[m];
        float nkr = ur * Vpr - ui * Vpi + vr * Vmr + vi * Vmi;
        float nki = ur * Vpi + ui * Vpr + vr * Vmi - vi * Vmr;
        float nmr = vr * Vpr + vi * Vpi + ur * Vmr - ui * Vmi;
        float nmi = vi * Vpr - vr * Vpi - ur * Vmi - ui * Vmr;
        gr[k] = nkr; gi[k] = nki; gr[m] = nmr; gi[m] = nmi;
      }
    } else {
      // regular: column k2 = s (stored doubled -> weight * 1/512), interleaved
      const float* wp = w + (size_t)(s * 768 + c) * 2;
#pragma unroll
      for (int k1 = 0; k1 < 16; k1++) {
        float2 wv2 = *(const float2*)(wp + (size_t)k1 * 13824);
        const float wr_ = wv2.x * INV512, wi_ = wv2.y * INV512;
        float yr = gr[k1] * wr_ - gi[k1] * wi_;
        float yi = gr[k1] * wi_ + gi[k1] * wr_;
        gr[k1] = yr; gi[k1] = yi;
      }
    }
    fft16<1>(gr, gi);

    // overwrite U with Q in place: every write depends on all 16 reads
    // (through the FFTs), so dataflow keeps reads-before-writes.
#pragma unroll
    for (int n1 = 0; n1 < 16; n1++) { Ew[66 * n1 + l] = packh2(gr[n1], gi[n1]); }
  }
  asm volatile("" ::: "memory");   // order S2 LDS writes before S3 LDS reads

  // ---------------- S3: irfft over k2, 2 channels packed; lane=(n1,pp) -----
  {
    const int n1 = l >> 2, pp = l & 3;
    float hr[16], hq[16];
#pragma unroll
    for (int k = 0; k <= 7; k++) {
      uint2 v = *(const uint2*)&Ew[66 * n1 + 8 * k + 2 * pp];
      float2 lo = unpackh2(v.x);   // (a.re, a.im)  /  k=0: (Q0_a, Q8_a)
      float2 hi = unpackh2(v.y);   // (b.re, b.im)  /  k=0: (Q0_b, Q8_b)
      if (k == 0) {
        hr[0] = lo.x; hq[0] = hi.x;
        hr[8] = lo.y; hq[8] = hi.y;
      } else {
        hr[k] = lo.x - hi.y;      hq[k] = lo.y + hi.x;
        hr[16 - k] = lo.x + hi.y; hq[16 - k] = hi.x - lo.y;
      }
    }
    fft16<1>(hr, hq);   // (re, im) = (out_a[n2], out_b[n2])
    float2* op = (float2*)(out + (size_t)b * 196608 + (size_t)n1 * 12288 + cb) + pp;
#pragma unroll
    for (int n2 = 0; n2 < 16; n2++) { op[n2 * 384] = make_float2(hr[n2], hq[n2]); }
  }
}

extern "C" void kernel_launch(void* const* d_in, const int* in_sizes, int n_in,
                              void* d_out, int out_size, void* d_ws, size_t ws_size,
                              hipStream_t stream) {
  const float* x = (const float*)d_in[0];
  const float* w = (const float*)d_in[1];
  float* out = (float*)d_out;
  dim3 grid(NCT * 256);   // 24 * 256 = 6144
  dim3 block(256);
  hipLaunchKernelGGL(gf7_kernel, grid, block, 0, stream, x, w, out);
}

// Round 8
// 120.395 us; speedup vs baseline: 1.5710x; 1.0246x over previous
//
#include <hip/hip_runtime.h>

// out = irfft2( rfft2(x_grid) * W ), ortho, grid 16x16, C=768, B=256.
// Block = fixed ct (32 ch), loops over TPB=8 batches. Cross-tile pipeline:
// next tile's x prefetched into LDS xs via global_load_lds (no VGPR cost),
// issued mid-S2 so HBM latency hides under S2-tail+S3 compute. Intra-tile
// barriers are raw s_barrier + lgkmcnt(0) only (NOT __syncthreads) so the
// prefetch stays in flight across them; tile-end barrier drains vmcnt(0).
// Compute/E-layout/numerics identical to R5 (absmax 9.8e-4, 0 conflicts).
// VGPR law (R4-R6): alloc ~= 2x VGPR_Count; 64-reg cap ((256,4)) is the
// only no-spill point -> ~13 waves/CU; this round adds ILP instead of TLP.

#define DIM 768
#define CT 32
#define NCT (DIM / CT)   // 24
#define TPB 8            // tiles (batches) per block
#define IP 258           // u32 pitch per i-row of E

#define R2c  0.70710678118654752f
#define C1c  0.92387953251128674f
#define S1cc 0.38268343236508978f
#define INV512  (1.f / 512.f)
#define INV256  (1.f / 256.f)
#define INV1024 (1.f / 1024.f)

typedef __fp16 h2v __attribute__((ext_vector_type(2)));
union H2U { h2v h; uint32_t u; };

__device__ __forceinline__ uint32_t packh2(float a, float b) {
  H2U t; t.h = __builtin_amdgcn_cvt_pkrtz(a, b); return t.u;
}
__device__ __forceinline__ float2 unpackh2(uint32_t v) {
  H2U t; t.u = v; return make_float2((float)t.h.x, (float)t.h.y);
}

typedef __attribute__((address_space(3))) void lds_void_t;
typedef __attribute__((address_space(1))) void glb_void_t;
__device__ __forceinline__ void gload16(const float* g, const float* l) {
  // async global->LDS, 16B per lane; LDS dst is wave-uniform base + lane*16
  __builtin_amdgcn_global_load_lds((glb_void_t*)(uintptr_t)g,
                                   (lds_void_t*)(uint32_t)(uintptr_t)l, 16, 0, 0);
}

#define BAR_LGKM() { asm volatile("s_waitcnt lgkmcnt(0)" ::: "memory"); __builtin_amdgcn_s_barrier(); }
#define BAR_ALL()  { asm volatile("s_waitcnt vmcnt(0) lgkmcnt(0)" ::: "memory"); __builtin_amdgcn_s_barrier(); }

template <int SGN>   // SGN = -1 forward, +1 inverse (unnormalized)
__device__ __forceinline__ void fft16(float* xr, float* xi) {
#define SWP(a, b) { float t_ = xr[a]; xr[a] = xr[b]; xr[b] = t_; t_ = xi[a]; xi[a] = xi[b]; xi[b] = t_; }
  SWP(1, 8) SWP(2, 4) SWP(3, 12) SWP(5, 10) SWP(7, 14) SWP(11, 13)
#undef SWP
#define BF1(a, b) { float tr = xr[b], ti = xi[b]; xr[b] = xr[a] - tr; xi[b] = xi[a] - ti; xr[a] += tr; xi[a] += ti; }
#define BFI(a, b) { float tr, ti; if (SGN < 0) { tr = xi[b]; ti = -xr[b]; } else { tr = -xi[b]; ti = xr[b]; } \
                    xr[b] = xr[a] - tr; xi[b] = xi[a] - ti; xr[a] += tr; xi[a] += ti; }
#define BFW(a, b, Wr, Wi) { float tr = (Wr) * xr[b] - (Wi) * xi[b], ti = (Wr) * xi[b] + (Wi) * xr[b]; \
                            xr[b] = xr[a] - tr; xi[b] = xi[a] - ti; xr[a] += tr; xi[a] += ti; }
  BF1(0, 1) BF1(2, 3) BF1(4, 5) BF1(6, 7) BF1(8, 9) BF1(10, 11) BF1(12, 13) BF1(14, 15)
  BF1(0, 2) BF1(4, 6) BF1(8, 10) BF1(12, 14)
  BFI(1, 3) BFI(5, 7) BFI(9, 11) BFI(13, 15)
  BF1(0, 4) BF1(8, 12)
  BFW(1, 5, R2c, SGN * R2c) BFW(9, 13, R2c, SGN * R2c)
  BFI(2, 6) BFI(10, 14)
  BFW(3, 7, -R2c, SGN * R2c) BFW(11, 15, -R2c, SGN * R2c)
  BF1(0, 8)
  BFW(1, 9, C1c, SGN * S1cc)
  BFW(2, 10, R2c, SGN * R2c)
  BFW(3, 11, S1cc, SGN * C1c)
  BFI(4, 12)
  BFW(5, 13, -S1cc, SGN * C1c)
  BFW(6, 14, -R2c, SGN * R2c)
  BFW(7, 15, -C1c, SGN * S1cc)
#undef BF1
#undef BFI
#undef BFW
}

__global__ __launch_bounds__(256, 4) void gf8_kernel(const float* __restrict__ x,
                                                     const float* __restrict__ w,
                                                     float* __restrict__ out) {
  __shared__ __align__(16) uint32_t E[16 * IP];   // 16.5 KB f16 spectra
  __shared__ __align__(16) float xs[8192];        // 32 KB staged x tile [256 tok][32 ch]

  const int blk = blockIdx.x;
  const int ct = blk >> 5;        // 0..23 fixed per block (W slice L2-hot)
  const int bg = blk & 31;        // batch group
  const int c0 = ct * CT;
  const int t  = threadIdx.x;
  const int wv = t >> 6;          // wave 0..3
  const int l  = t & 63;          // lane
  const int r  = t >> 4;          // i (S1) / n1 (S3)
  const int p  = t & 15;          // channel-pair index

  // prefetch geometry: wave wv stages tokens [wv*64, wv*64+63]; 8 instrs of
  // 1KB (8 token-rows x 128B); lane l -> token +(l>>3), 16B granule (l&7).
  const float* gsrc0 = x + c0 + (size_t)(wv * 64 + (l >> 3)) * DIM + (l & 7) * 4;
  const float* ldst0 = xs + wv * 2048;   // wave-uniform

#define PREF(bb) {                                                         \
    const float* gs_ = gsrc0 + (size_t)(bb) * 196608;                      \
    _Pragma("unroll")                                                      \
    for (int q_ = 0; q_ < 8; ++q_)                                         \
      gload16(gs_ + q_ * 8 * DIM, ldst0 + q_ * 256);                       \
  }

  // ---- prologue: stage tile 0 ----
  PREF(bg * TPB);
  __syncthreads();

#pragma unroll 1
  for (int it = 0; it < TPB; ++it) {
    const int b = bg * TPB + it;

    // ---------------- S1: rfft over j from xs, 2 channels packed ----------
    {
      const float2* xp = (const float2*)xs + r * 256 + p;
      float zr[16], zi[16];
#pragma unroll
      for (int j = 0; j < 16; j++) { float2 v = xp[j * 16]; zr[j] = v.x; zi[j] = v.y; }
      fft16<-1>(zr, zi);
      {
        uint2 v; v.x = packh2(zr[0], zr[8]); v.y = packh2(zi[0], zi[8]);
        *(uint2*)&E[2 * (r * 129 + p)] = v;
      }
#pragma unroll
      for (int k = 1; k <= 7; k++) {
        const int m = 16 - k;
        float Ar = zr[k] + zr[m], Ai = zi[k] - zi[m];
        float Br = zi[k] + zi[m], Bi = zr[m] - zr[k];
        uint2 v; v.x = packh2(Ar, Ai); v.y = packh2(Br, Bi);
        *(uint2*)&E[2 * (r * 129 + k * 16 + p)] = v;
      }
    }
    BAR_LGKM();

    // ---------------- S2: fft over i, weight, ifft over k1 ----------------
    {
      const int s = t >> 5;         // slot 0..7
      const int c = t & 31;         // channel within tile
      float gr[16], gi[16];
      const uint32_t* col = E + s * 32 + c;
#pragma unroll
      for (int i = 0; i < 16; i++) { float2 v = unpackh2(col[i * IP]); gr[i] = v.x; gi[i] = v.y; }
      BAR_LGKM();                   // all E reads done before Q overwrites

      fft16<-1>(gr, gi);
      if (s == 0) {
        const float* wc = w + (size_t)(c0 + c) * 2;
        {
          float2 a0 = *(const float2*)(wc);
          float2 a8 = *(const float2*)(wc + 12288);
          float2 b0 = *(const float2*)(wc + 8 * 13824);
          float2 b8 = *(const float2*)(wc + 8 * 13824 + 12288);
          gr[0] = gr[0] * (a0.x * INV256);
          gi[0] = gi[0] * (a8.x * INV256);
          gr[8] = gr[8] * (b0.x * INV256);
          gi[8] = gi[8] * (b8.x * INV256);
        }
#pragma unroll
        for (int k = 1; k <= 7; k++) {
          const int m = 16 - k;
          float2 a0 = *(const float2*)(wc + (size_t)k * 13824);
          float2 m0 = *(const float2*)(wc + (size_t)m * 13824);
          float2 a8 = *(const float2*)(wc + (size_t)k * 13824 + 12288);
          float2 m8 = *(const float2*)(wc + (size_t)m * 13824 + 12288);
          float Vpr = (a0.x + m0.x + a8.x + m8.x) * INV1024;
          float Vpi = (a0.y - m0.y + a8.y - m8.y) * INV1024;
          float Vmr = (a0.x + m0.x - a8.x - m8.x) * INV1024;
          float Vmi = (a0.y - m0.y - a8.y + m8.y) * INV1024;
          float ur = gr[k], ui = gi[k], vr = gr[m], vi = gi[m];
          float nkr = ur * Vpr - ui * Vpi + vr * Vmr + vi * Vmi;
          float nki = ur * Vpi + ui * Vpr + vr * Vmi - vi * Vmr;
          float nmr = vr * Vpr + vi * Vpi + ur * Vmr - ui * Vmi;
          float nmi = vi * Vpr - vr * Vpi - ur * Vmi - ui * Vmr;
          gr[k] = nkr; gi[k] = nki; gr[m] = nmr; gi[m] = nmi;
        }
      } else {
        const float* wp = w + (size_t)(s * 768 + c0 + c) * 2;
#pragma unroll
        for (int k1 = 0; k1 < 16; k1++) {
          float2 wv2 = *(const float2*)(wp + (size_t)k1 * 13824);
          const float wr_ = wv2.x * INV512, wi_ = wv2.y * INV512;
          float yr = gr[k1] * wr_ - gi[k1] * wi_;
          float yi = gr[k1] * wi_ + gi[k1] * wr_;
          gr[k1] = yr; gi[k1] = yi;
        }
      }
      fft16<1>(gr, gi);

      // weights consumed; stage next tile's x (overwrites xs, safe: all S1
      // reads finished at first barrier). Stays in flight across lgkm bars.
      asm volatile("" ::: "memory");
      if (it + 1 < TPB) PREF(b + 1);

      uint32_t* colo = E + s * 32 + c;
#pragma unroll
      for (int n1 = 0; n1 < 16; n1++) { colo[n1 * IP] = packh2(gr[n1], gi[n1]); }
    }
    BAR_LGKM();

    // ---------------- S3: irfft over k2, 2 channels packed, store ---------
    {
      float hr[16], hq[16];
#pragma unroll
      for (int k = 0; k <= 7; k++) {
        uint2 v = *(const uint2*)&E[2 * (r * 129 + k * 16 + p)];
        float2 lo = unpackh2(v.x);
        float2 hi = unpackh2(v.y);
        if (k == 0) {
          hr[0] = lo.x; hq[0] = hi.x;
          hr[8] = lo.y; hq[8] = hi.y;
        } else {
          hr[k] = lo.x - hi.y;      hq[k] = lo.y + hi.x;
          hr[16 - k] = lo.x + hi.y; hq[16 - k] = hi.x - lo.y;
        }
      }
      fft16<1>(hr, hq);
      float2* op = (float2*)(out + (size_t)b * 196608 + (size_t)r * 12288 + c0) + p;
#pragma unroll
      for (int n2 = 0; n2 < 16; n2++) { op[n2 * 384] = make_float2(hr[n2], hq[n2]); }
    }
    // drain: prefetch (issued ~1000cy ago, mostly complete) + stores; also
    // orders E reads (S3) before next tile's S1 E-writes.
    BAR_ALL();
  }
}

extern "C" void kernel_launch(void* const* d_in, const int* in_sizes, int n_in,
                              void* d_out, int out_size, void* d_ws, size_t ws_size,
                              hipStream_t stream) {
  const float* x = (const float*)d_in[0];
  const float* w = (const float*)d_in[1];
  float* out = (float*)d_out;
  dim3 grid(NCT * 32);   // 24 ct x 32 batch-groups = 768 blocks (all resident)
  dim3 block(256);
  hipLaunchKernelGGL(gf8_kernel, grid, block, 0, stream, x, w, out);
}